// Round 1
// baseline (6377.382 us; speedup 1.0000x reference)
//
#include <hip/hip_runtime.h>
#include <math.h>

// Problem constants (fixed by reference setup_inputs)
#define B_    512
#define S_    128
#define H_    512
#define H3_   1536
#define IV_   8192
#define OUTC_ 129           // S+1
#define CHUNK_ 16512        // 66048 / 4 rows per MLP chunk (divisible by 64)
#define EOS_  1

// ---------------------------------------------------------------------------
// h0[b][:] = stem_emb[stem_batch[b]][:]
__global__ __launch_bounds__(256)
void build_h0(const int* __restrict__ stem_batch,
              const float* __restrict__ stem_emb,
              float* __restrict__ h0) {
    int i = blockIdx.x * blockDim.x + threadIdx.x;   // over B*H/4 float4s
    int b = i >> 7;            // /128
    int c = (i & 127) << 2;    // *4
    int row = stem_batch[b];
    float4 v = *(const float4*)&stem_emb[(size_t)row * H_ + c];
    *(float4*)&h0[(size_t)b * H_ + c] = v;
}

// ---------------------------------------------------------------------------
// C[m][n] = act( opt_relu(A[m][:]) dot W[n][:] + bias[n] )
// A: [M,K] row-major, W: [N,K] row-major (i.e. computes A @ W^T + b)
// BM=BN=64, BK=32, 256 threads, 4x4 micro-tile per thread.
template<bool RELU_IN, bool RELU_OUT>
__global__ __launch_bounds__(256)
void gemm_nt(const float* __restrict__ A, const float* __restrict__ W,
             const float* __restrict__ bias, float* __restrict__ C,
             int M, int N, int K) {
    __shared__ float As[64][33];
    __shared__ float Ws[64][33];
    const int tid = threadIdx.x;
    const int bm = blockIdx.y * 64;
    const int bn = blockIdx.x * 64;
    const int tx = tid & 15;        // 0..15
    const int ty = tid >> 4;        // 0..15
    const int lr = tid >> 3;        // 0..31 (load row)
    const int lc = (tid & 7) << 2;  // 0,4,..,28 (load col*4)

    float acc[4][4] = {};

    for (int k0 = 0; k0 < K; k0 += 32) {
        float4 a0 = *(const float4*)&A[(size_t)(bm + lr)      * K + k0 + lc];
        float4 a1 = *(const float4*)&A[(size_t)(bm + lr + 32) * K + k0 + lc];
        float4 w0 = *(const float4*)&W[(size_t)(bn + lr)      * K + k0 + lc];
        float4 w1 = *(const float4*)&W[(size_t)(bn + lr + 32) * K + k0 + lc];
        if (RELU_IN) {
            a0.x = fmaxf(a0.x, 0.f); a0.y = fmaxf(a0.y, 0.f);
            a0.z = fmaxf(a0.z, 0.f); a0.w = fmaxf(a0.w, 0.f);
            a1.x = fmaxf(a1.x, 0.f); a1.y = fmaxf(a1.y, 0.f);
            a1.z = fmaxf(a1.z, 0.f); a1.w = fmaxf(a1.w, 0.f);
        }
        __syncthreads();   // previous-iter compute done before overwrite
        *(float4*)&As[lr][lc]      = a0;
        *(float4*)&As[lr + 32][lc] = a1;
        *(float4*)&Ws[lr][lc]      = w0;
        *(float4*)&Ws[lr + 32][lc] = w1;
        __syncthreads();
        #pragma unroll
        for (int kk = 0; kk < 32; ++kk) {
            float av[4], wv[4];
            #pragma unroll
            for (int i = 0; i < 4; ++i) av[i] = As[ty * 4 + i][kk];
            #pragma unroll
            for (int j = 0; j < 4; ++j) wv[j] = Ws[tx * 4 + j][kk];
            #pragma unroll
            for (int i = 0; i < 4; ++i)
                #pragma unroll
                for (int j = 0; j < 4; ++j)
                    acc[i][j] += av[i] * wv[j];
        }
    }

    #pragma unroll
    for (int i = 0; i < 4; ++i) {
        int m = bm + ty * 4 + i;
        #pragma unroll
        for (int j = 0; j < 4; ++j) {
            int n = bn + tx * 4 + j;
            float c = acc[i][j] + bias[n];
            if (RELU_OUT) c = fmaxf(c, 0.f);
            C[(size_t)m * N + n] = c;
        }
    }
}

// ---------------------------------------------------------------------------
// One GRU step: h_out[b][j] from h_in and precomputed GW (gi incl. b_ih).
// gh = h_in @ W_hh^T + b_hh computed tiled; gates fused in epilogue.
// BM=BN=32 (b x j), BK=64, 256 threads, 2x2 micro-tile, 3 gates.
__global__ __launch_bounds__(256)
void gru_step(const float* __restrict__ h_in, float* __restrict__ h_out,
              const float* __restrict__ GW, const int* __restrict__ goal,
              int t, const float* __restrict__ W_hh,
              const float* __restrict__ b_hh) {
    __shared__ float Hs[32][65];
    __shared__ float Wr[32][65];
    __shared__ float Wz[32][65];
    __shared__ float Wn[32][65];
    const int tid = threadIdx.x;
    const int bm = blockIdx.y * 32;   // batch rows
    const int bn = blockIdx.x * 32;   // hidden cols
    const int tx = tid & 15;
    const int ty = tid >> 4;
    const int lr = tid >> 4;          // 0..15
    const int lc = (tid & 15) << 2;   // 0..60

    float ar[2][2] = {}, az[2][2] = {}, an[2][2] = {};

    for (int k0 = 0; k0 < H_; k0 += 64) {
        float4 h0v = *(const float4*)&h_in[(size_t)(bm + lr)      * H_ + k0 + lc];
        float4 h1v = *(const float4*)&h_in[(size_t)(bm + lr + 16) * H_ + k0 + lc];
        float4 r0 = *(const float4*)&W_hh[(size_t)(bn + lr)              * H_ + k0 + lc];
        float4 r1 = *(const float4*)&W_hh[(size_t)(bn + lr + 16)         * H_ + k0 + lc];
        float4 z0 = *(const float4*)&W_hh[(size_t)(512 + bn + lr)        * H_ + k0 + lc];
        float4 z1 = *(const float4*)&W_hh[(size_t)(512 + bn + lr + 16)   * H_ + k0 + lc];
        float4 n0 = *(const float4*)&W_hh[(size_t)(1024 + bn + lr)       * H_ + k0 + lc];
        float4 n1 = *(const float4*)&W_hh[(size_t)(1024 + bn + lr + 16)  * H_ + k0 + lc];
        __syncthreads();
        *(float4*)&Hs[lr][lc]      = h0v;
        *(float4*)&Hs[lr + 16][lc] = h1v;
        *(float4*)&Wr[lr][lc]      = r0;
        *(float4*)&Wr[lr + 16][lc] = r1;
        *(float4*)&Wz[lr][lc]      = z0;
        *(float4*)&Wz[lr + 16][lc] = z1;
        *(float4*)&Wn[lr][lc]      = n0;
        *(float4*)&Wn[lr + 16][lc] = n1;
        __syncthreads();
        #pragma unroll
        for (int kk = 0; kk < 64; ++kk) {
            float hm0 = Hs[ty * 2][kk],     hm1 = Hs[ty * 2 + 1][kk];
            float wr0 = Wr[tx * 2][kk],     wr1 = Wr[tx * 2 + 1][kk];
            float wz0 = Wz[tx * 2][kk],     wz1 = Wz[tx * 2 + 1][kk];
            float wn0 = Wn[tx * 2][kk],     wn1 = Wn[tx * 2 + 1][kk];
            ar[0][0] += hm0 * wr0; ar[0][1] += hm0 * wr1;
            ar[1][0] += hm1 * wr0; ar[1][1] += hm1 * wr1;
            az[0][0] += hm0 * wz0; az[0][1] += hm0 * wz1;
            az[1][0] += hm1 * wz0; az[1][1] += hm1 * wz1;
            an[0][0] += hm0 * wn0; an[0][1] += hm0 * wn1;
            an[1][0] += hm1 * wn0; an[1][1] += hm1 * wn1;
        }
    }

    #pragma unroll
    for (int i = 0; i < 2; ++i) {
        int b = bm + ty * 2 + i;
        int grow = (t < S_) ? goal[(size_t)b * S_ + t] : EOS_;
        const float* gw = GW + (size_t)grow * H3_;
        #pragma unroll
        for (int jj = 0; jj < 2; ++jj) {
            int j = bn + tx * 2 + jj;
            float gir = gw[j];
            float giz = gw[j + 512];
            float gin = gw[j + 1024];
            float ghr = ar[i][jj] + b_hh[j];
            float ghz = az[i][jj] + b_hh[j + 512];
            float ghn = an[i][jj] + b_hh[j + 1024];
            float r = 1.f / (1.f + expf(-(gir + ghr)));
            float z = 1.f / (1.f + expf(-(giz + ghz)));
            float n = tanhf(gin + r * ghn);
            float hp = h_in[(size_t)b * H_ + j];
            h_out[(size_t)b * H_ + j] = (1.f - z) * n + z * hp;
        }
    }
}

// ---------------------------------------------------------------------------
// logit[row] = Y2[row][:] dot out_W + out_b, scattered into d_out[b][pos].
// One wave per row, 4 waves per block.
__global__ __launch_bounds__(256)
void gemv_out(const float* __restrict__ Y2, const float* __restrict__ outW,
              const float* __restrict__ outb, float* __restrict__ out,
              int row0) {
    int wave = threadIdx.x >> 6;
    int lane = threadIdx.x & 63;
    int row = blockIdx.x * 4 + wave;
    const float* y = Y2 + (size_t)row * H_;
    float4 v0 = *(const float4*)&y[lane * 4];
    float4 v1 = *(const float4*)&y[256 + lane * 4];
    float4 w0 = *(const float4*)&outW[lane * 4];
    float4 w1 = *(const float4*)&outW[256 + lane * 4];
    float s = v0.x * w0.x + v0.y * w0.y + v0.z * w0.z + v0.w * w0.w
            + v1.x * w1.x + v1.y * w1.y + v1.z * w1.z + v1.w * w1.w;
    #pragma unroll
    for (int off = 32; off > 0; off >>= 1) s += __shfl_down(s, off);
    if (lane == 0) {
        int r = row0 + row;
        int t = r / B_;
        int b = r - t * B_;
        int pos = (t == S_) ? 0 : t + 1;
        out[(size_t)b * OUTC_ + pos] = s + outb[0];
    }
}

// ---------------------------------------------------------------------------
// In-place log_softmax over each row of d_out [B][129]. One wave per row.
__global__ __launch_bounds__(64)
void logsoftmax_rows(float* __restrict__ out) {
    int b = blockIdx.x;
    int lane = threadIdx.x;
    float* row = out + (size_t)b * OUTC_;
    float x0 = row[lane];
    float x1 = row[lane + 64];                      // 64..127
    float x2 = (lane == 0) ? row[128] : -INFINITY;  // last element
    float m = fmaxf(fmaxf(x0, x1), x2);
    #pragma unroll
    for (int off = 32; off > 0; off >>= 1) m = fmaxf(m, __shfl_xor(m, off));
    float s = expf(x0 - m) + expf(x1 - m) + ((lane == 0) ? expf(x2 - m) : 0.f);
    #pragma unroll
    for (int off = 32; off > 0; off >>= 1) s += __shfl_xor(s, off);
    float ls = m + logf(s);
    row[lane] = x0 - ls;
    row[lane + 64] = x1 - ls;
    if (lane == 0) row[128] = x2 - ls;
}

// ---------------------------------------------------------------------------
extern "C" void kernel_launch(void* const* d_in, const int* in_sizes, int n_in,
                              void* d_out, int out_size, void* d_ws, size_t ws_size,
                              hipStream_t stream) {
    const int*   goal     = (const int*)d_in[0];
    const int*   stem     = (const int*)d_in[1];
    const float* stem_emb = (const float*)d_in[2];
    const float* word_emb = (const float*)d_in[3];
    const float* W_ih     = (const float*)d_in[4];
    const float* W_hh     = (const float*)d_in[5];
    const float* b_ih     = (const float*)d_in[6];
    const float* b_hh     = (const float*)d_in[7];
    const float* in_W     = (const float*)d_in[8];
    const float* in_b     = (const float*)d_in[9];
    const float* l0_W     = (const float*)d_in[10];
    const float* l0_b     = (const float*)d_in[11];
    const float* out_W    = (const float*)d_in[12];
    const float* out_b    = (const float*)d_in[13];
    float* out = (float*)d_out;

    // Workspace layout (floats):
    //   GW : [IV][3H]       relu(word_emb) @ W_ih^T + b_ih   (48 MiB)
    //   HS : [S+2][B][H]    slot0=h0, slot t+1=hs[t], slot S+1=h_final (130 MiB)
    //   Y1 : [CHUNK][H]     MLP layer 1 activations          (32 MiB)
    //   Y2 : [CHUNK][H]     MLP layer 2 activations          (32 MiB)
    float* GW = (float*)d_ws;
    float* HS = GW + (size_t)IV_ * H3_;
    float* Y1 = HS + (size_t)(S_ + 2) * B_ * H_;
    float* Y2 = Y1 + (size_t)CHUNK_ * H_;

    // h0 gather
    build_h0<<<(B_ * H_ / 4) / 256, 256, 0, stream>>>(stem, stem_emb, HS);

    // Vocabulary-factored input projection: GW = relu(word_emb) @ W_ih^T + b_ih
    gemm_nt<true, false><<<dim3(H3_ / 64, IV_ / 64), 256, 0, stream>>>(
        word_emb, W_ih, b_ih, GW, IV_, H3_, H_);

    // Sequential GRU: step t reads HS slot t, writes slot t+1. t==S is EOS step.
    for (int t = 0; t <= S_; ++t) {
        gru_step<<<dim3(H_ / 32, B_ / 32), 256, 0, stream>>>(
            HS + (size_t)t * B_ * H_, HS + (size_t)(t + 1) * B_ * H_,
            GW, goal, t, W_hh, b_hh);
    }

    // MLP head over all (S+1)*B = 66048 states (slots 1..S+1), chunked.
    for (int c = 0; c < 4; ++c) {
        const float* hsrc = HS + (size_t)B_ * H_ + (size_t)c * CHUNK_ * H_;
        gemm_nt<true, true><<<dim3(H_ / 64, CHUNK_ / 64), 256, 0, stream>>>(
            hsrc, in_W, in_b, Y1, CHUNK_, H_, H_);
        gemm_nt<false, true><<<dim3(H_ / 64, CHUNK_ / 64), 256, 0, stream>>>(
            Y1, l0_W, l0_b, Y2, CHUNK_, H_, H_);
        gemv_out<<<CHUNK_ / 4, 256, 0, stream>>>(Y2, out_W, out_b, out, c * CHUNK_);
    }

    // Row-wise log_softmax in place.
    logsoftmax_rows<<<B_, 64, 0, stream>>>(out);
}